// Round 9
// baseline (918.247 us; speedup 1.0000x reference)
//
#include <hip/hip_runtime.h>

#define NTOK 262144   // 64*64*64 tokens per batch
#define NCH  64
#define NB   4

#define BTOK 256      // tokens per block per iteration (4 waves x 64)
#define NIT  4        // iterations per block
#define GRIDX (NTOK / (BTOK * NIT))   // 256 blocks per batch

// ws layout (floats): S[4][4] @0, m[4][4][64] @16, rc[4][64] @1040
#define WS_S  0
#define WS_M  16
#define WS_RC 1040

typedef float floatx4 __attribute__((ext_vector_type(4)));   // native vec for nontemporal

// Fused keys+msum: x read from HBM exactly once.
// Lane layout: q = l>>4 owns channels [16q,16q+16); lh = l&15 owns tokens
// lh*4..+3 of the wave's 64-token tile. Live set ~170 VGPR: xr[16]=64 +
// macc[64]=64 + k/e + addresses. amdgpu_waves_per_eu(1,2) caps the
// allocator's occupancy target at 2 waves/EU (256-VGPR budget) so it does
// NOT spill (r5/r8 lesson: launch_bounds' min alone still lets the
// allocator chase 4 waves/EU = 128-VGPR cap and spill to scratch).
__global__ __launch_bounds__(256)
__attribute__((amdgpu_waves_per_eu(1, 2)))
void ea3d_fused(const float* __restrict__ x, const float* __restrict__ Wk,
                float* __restrict__ ws)
{
    __shared__ __align__(16) float wk4[NCH * 4];   // wk4[c][h]
    __shared__ float ssum[4][4];

    const int tid = threadIdx.x;
    const int w   = tid >> 6;
    const int l   = tid & 63;
    const int b   = blockIdx.y;

    { int c = tid >> 2, h = tid & 3; wk4[(c << 2) + h] = Wk[h * NCH + c]; }
    __syncthreads();

    const int q  = l >> 4;
    const int lh = l & 15;
    const int c0 = q << 4;
    const float* xb = x + ((size_t)b * NCH + c0) * NTOK;

    float macc[64];                    // macc[i*4+h], channel c0+i — static only
    #pragma unroll
    for (int r = 0; r < 64; ++r) macc[r] = 0.f;
    float sacc[4] = {0.f, 0.f, 0.f, 0.f};

    for (int it = 0; it < NIT; ++it) {
        const size_t n0 = ((size_t)blockIdx.x * NIT + it) * BTOK + (w << 6) + (lh << 2);

        // ---- single global read of this tile slice: 16 channel rows x 4 tokens ----
        float4 xr[16];
        #pragma unroll
        for (int i = 0; i < 16; ++i)
            xr[i] = *(const float4*)(xb + (size_t)i * NTOK + n0);

        // ---- keys partial over this lane's 16 channels ----
        float k[16];   // k[h*4 + j]
        #pragma unroll
        for (int r = 0; r < 16; ++r) k[r] = 0.f;
        #pragma unroll
        for (int i = 0; i < 16; ++i) {
            float4 wv = *((const float4*)wk4 + (c0 + i));
            float4 xv = xr[i];
            k[0]  += wv.x * xv.x; k[1]  += wv.x * xv.y; k[2]  += wv.x * xv.z; k[3]  += wv.x * xv.w;
            k[4]  += wv.y * xv.x; k[5]  += wv.y * xv.y; k[6]  += wv.y * xv.z; k[7]  += wv.y * xv.w;
            k[8]  += wv.z * xv.x; k[9]  += wv.z * xv.y; k[10] += wv.z * xv.z; k[11] += wv.z * xv.w;
            k[12] += wv.w * xv.x; k[13] += wv.w * xv.y; k[14] += wv.w * xv.z; k[15] += wv.w * xv.w;
        }
        // combine the 4 channel quarters: lanes {l, l^16, l^32, l^48}
        #pragma unroll
        for (int r = 0; r < 16; ++r) {
            k[r] += __shfl_xor(k[r], 16);
            k[r] += __shfl_xor(k[r], 32);
        }

        // ---- e = exp(k); S partial (each token counted 4x -> scale later) ----
        float e[16];
        #pragma unroll
        for (int r = 0; r < 16; ++r) e[r] = __expf(k[r]);
        #pragma unroll
        for (int h = 0; h < 4; ++h)
            sacc[h] += (e[h*4+0] + e[h*4+1]) + (e[h*4+2] + e[h*4+3]);

        // ---- m accumulation, all in registers, all static ----
        #pragma unroll
        for (int i = 0; i < 16; ++i) {
            float4 xv = xr[i];
            macc[i*4+0] += e[0] *xv.x + e[1] *xv.y + e[2] *xv.z + e[3] *xv.w;
            macc[i*4+1] += e[4] *xv.x + e[5] *xv.y + e[6] *xv.z + e[7] *xv.w;
            macc[i*4+2] += e[8] *xv.x + e[9] *xv.y + e[10]*xv.z + e[11]*xv.w;
            macc[i*4+3] += e[12]*xv.x + e[13]*xv.y + e[14]*xv.z + e[15]*xv.w;
        }
    }

    // ---- final: reduce macc across the 16 token-lanes (same q) ----
    #pragma unroll
    for (int r = 0; r < 64; ++r) {
        float v = macc[r];
        v += __shfl_xor(v, 1);
        v += __shfl_xor(v, 2);
        v += __shfl_xor(v, 4);
        v += __shfl_xor(v, 8);
        macc[r] = v;
    }
    if (lh == 0) {     // lanes 0,16,32,48: disjoint channel quarters
        float* mb = ws + WS_M + (size_t)(b * 4) * NCH + c0;
        #pragma unroll
        for (int i = 0; i < 16; ++i) {
            #pragma unroll
            for (int h = 0; h < 4; ++h)
                __hip_atomic_fetch_add(mb + h * NCH + i, macc[i*4+h],
                                       __ATOMIC_RELAXED, __HIP_MEMORY_SCOPE_AGENT);
        }
    }

    // ---- S: reduce over 64 lanes (4x duplication -> 0.25), block, then global ----
    #pragma unroll
    for (int h = 0; h < 4; ++h) {
        float v = sacc[h];
        #pragma unroll
        for (int off = 32; off; off >>= 1) v += __shfl_xor(v, off);
        sacc[h] = 0.25f * v;
    }
    if (l == 0) {
        #pragma unroll
        for (int h = 0; h < 4; ++h) ssum[w][h] = sacc[h];
    }
    __syncthreads();
    if (tid < 4) {
        float s = (ssum[0][tid] + ssum[1][tid]) + (ssum[2][tid] + ssum[3][tid]);
        __hip_atomic_fetch_add(ws + WS_S + b * 4 + tid, s,
                               __ATOMIC_RELAXED, __HIP_MEMORY_SCOPE_AGENT);
    }
}

// ---------- finalize: context = Wv*(m/S)+bv ; rc = Wr*context + br ----------
__global__ void ea3d_finalize(const float* __restrict__ Wv, const float* __restrict__ bv,
                              const float* __restrict__ Wr, const float* __restrict__ br,
                              float* __restrict__ ws)
{
    __shared__ float ctx[NB * 32];
    const int tid = threadIdx.x;
    if (tid < 128) {
        int b = tid >> 5, hv = tid & 31, h = hv >> 3;
        float inv = 1.0f / ws[WS_S + b * 4 + h];
        const float* m = ws + WS_M + (b * 4 + h) * NCH;
        const float* wvr = Wv + hv * NCH;
        float acc = 0.f;
        #pragma unroll
        for (int c = 0; c < NCH; ++c) acc += wvr[c] * m[c];
        ctx[b * 32 + hv] = acc * inv + bv[hv];
    }
    __syncthreads();
    int b = tid >> 6, c = tid & 63;
    const float* wrr = Wr + c * 32;
    const float* cb  = ctx + b * 32;
    float acc = br[c];
    #pragma unroll
    for (int hv = 0; hv < 32; ++hv) acc += wrr[hv] * cb[hv];
    ws[WS_RC + b * NCH + c] = acc;
}

// ---------- out = x + rc[b][c]  (nontemporal stores: don't evict x) ----------
__global__ __launch_bounds__(256)
void ea3d_add(const float* __restrict__ x, const float* __restrict__ ws,
              float* __restrict__ out)
{
    const int row = blockIdx.y;                 // b*64 + c
    const float rc = ws[WS_RC + row];
    const size_t base = (size_t)row * NTOK;
    const float4*  xp = (const float4*)(x + base);
    floatx4*       op = (floatx4*)(out + base);
    const int nvec = NTOK / 4;
    for (int i = blockIdx.x * blockDim.x + threadIdx.x; i < nvec;
         i += gridDim.x * blockDim.x) {
        float4 v = xp[i];
        floatx4 nv = { v.x + rc, v.y + rc, v.z + rc, v.w + rc };
        __builtin_nontemporal_store(nv, op + i);
    }
}

extern "C" void kernel_launch(void* const* d_in, const int* in_sizes, int n_in,
                              void* d_out, int out_size, void* d_ws, size_t ws_size,
                              hipStream_t stream)
{
    const float* x  = (const float*)d_in[0];
    const float* Wk = (const float*)d_in[1];
    // d_in[2]=bk (cancels in token-softmax); d_in[3]=Wq, d_in[4]=bq (softmax over
    // size-1 head-channel axis -> identically 1.0, so Wq/bq are dead)
    const float* Wv = (const float*)d_in[5];
    const float* bv = (const float*)d_in[6];
    const float* Wr = (const float*)d_in[7];
    const float* br = (const float*)d_in[8];
    float* out = (float*)d_out;
    float* ws  = (float*)d_ws;

    (void)hipMemsetAsync(ws, 0, WS_RC * sizeof(float), stream);  // zero S + m accumulators
    ea3d_fused<<<dim3(GRIDX, NB), 256, 0, stream>>>(x, Wk, ws);
    ea3d_finalize<<<1, 256, 0, stream>>>(Wv, bv, Wr, br, ws);
    ea3d_add<<<dim3(32, NB * NCH), 256, 0, stream>>>(x, ws, out);
}

// Round 10
// 209.170 us; speedup vs baseline: 4.3900x; 4.3900x over previous
//
#include <hip/hip_runtime.h>

#define NTOK 262144   // 64*64*64 tokens per batch
#define NCH  64
#define NB   4

#define TPB   512     // 8 waves per block
#define TILE  128     // tokens per tile
#define GRIDX 128     // blocks per batch -> 512 total = 2/CU
#define NIT   (NTOK / (GRIDX * TILE))   // 16 consecutive tiles per block

// ws layout (floats): S[4][4] @0, m[4][4][64] @16, rc[4][64] @1040
#define WS_S  0
#define WS_M  16
#define WS_RC 1040

typedef float floatx4 __attribute__((ext_vector_type(4)));   // native vec for nontemporal

// Single-x-read reduce: keys + exp + m-accumulation, one 128-token tile per
// block-step. Wave w owns 8 channel rows; lane l owns tokens 2l,2l+1.
// Loads: float2/lane -> 512B contiguous per instruction; block's 16 tiles are
// consecutive -> 8KB sequential per channel row per block (DRAM-friendly).
// Cross-wave key combine via kpart LDS; e broadcast via es LDS; m stays in
// per-lane registers (macc[32], all static indexing).
__global__ __launch_bounds__(TPB)
void ea3d_reduce(const float* __restrict__ x, const float* __restrict__ Wk,
                 float* __restrict__ ws)
{
    __shared__ __align__(16) float wk4[NCH * 4];        // wk4[c][h]
    __shared__ __align__(16) float kpart[8 * TILE * 4]; // [w][tok][h]  16KB
    __shared__ __align__(16) float es[TILE * 4];        // [tok][h]      2KB
    __shared__ float ssum[8][4];

    const int tid = threadIdx.x;
    const int w   = tid >> 6;
    const int l   = tid & 63;
    const int b   = blockIdx.y;

    if (tid < 256) { int c = tid >> 2, h = tid & 3; wk4[(c << 2) + h] = Wk[h * NCH + c]; }
    __syncthreads();

    const int c0 = w << 3;                       // this wave's 8 channels
    const float* xb = x + ((size_t)b * NCH + c0) * NTOK;
    const size_t tokbase = (size_t)blockIdx.x * (TILE * NIT) + (l << 1);

    float macc[32];                              // macc[i*4+h], channel c0+i
    #pragma unroll
    for (int r = 0; r < 32; ++r) macc[r] = 0.f;
    float sacc = 0.f;                            // per-thread (tok,h) e-sum

    float2 xA[8], xB[8];
    {   // prologue: tile 0
        #pragma unroll
        for (int i = 0; i < 8; ++i)
            xA[i] = *(const float2*)(xb + (size_t)i * NTOK + tokbase);
    }

    auto body = [&](float2 (&cur)[8], float2 (&nxt)[8], int it) {
        // ---- keys partial (8 channels x lane's 2 tokens) ----
        float kk[8];                             // kk[h*2 + j]
        #pragma unroll
        for (int r = 0; r < 8; ++r) kk[r] = 0.f;
        #pragma unroll
        for (int i = 0; i < 8; ++i) {
            float4 wv = *((const float4*)wk4 + (c0 + i));
            kk[0] += wv.x * cur[i].x; kk[1] += wv.x * cur[i].y;
            kk[2] += wv.y * cur[i].x; kk[3] += wv.y * cur[i].y;
            kk[4] += wv.z * cur[i].x; kk[5] += wv.z * cur[i].y;
            kk[6] += wv.w * cur[i].x; kk[7] += wv.w * cur[i].y;
        }
        float4* kp = (float4*)(kpart + (w * TILE + (l << 1)) * 4);
        kp[0] = make_float4(kk[0], kk[2], kk[4], kk[6]);   // token 2l
        kp[1] = make_float4(kk[1], kk[3], kk[5], kk[7]);   // token 2l+1

        // ---- prefetch next tile; stays in flight across both barriers ----
        if (it + 1 < NIT) {
            const float* xp = xb + tokbase + (size_t)(it + 1) * TILE;
            #pragma unroll
            for (int i = 0; i < 8; ++i)
                nxt[i] = *(const float2*)(xp + (size_t)i * NTOK);
        }

        asm volatile("s_waitcnt lgkmcnt(0)" ::: "memory");
        __builtin_amdgcn_s_barrier();            // kpart ready (vmcnt NOT drained)
        asm volatile("" ::: "memory");

        // ---- exp phase: thread -> (tok = tid>>2, h = tid&3) ----
        {
            const int tok = tid >> 2, h = tid & 3;
            float kv = 0.f;
            #pragma unroll
            for (int w2 = 0; w2 < 8; ++w2)
                kv += kpart[(w2 * TILE + tok) * 4 + h];
            float e = __expf(kv);
            es[tok * 4 + h] = e;
            sacc += e;
        }

        asm volatile("s_waitcnt lgkmcnt(0)" ::: "memory");
        __builtin_amdgcn_s_barrier();            // es ready
        asm volatile("" ::: "memory");

        // ---- m accumulation (registers, static) ----
        {
            float4 e0 = *(const float4*)(es + (l << 1) * 4);
            float4 e1 = *(const float4*)(es + (l << 1) * 4 + 4);
            #pragma unroll
            for (int i = 0; i < 8; ++i) {
                macc[i*4+0] += e0.x * cur[i].x + e1.x * cur[i].y;
                macc[i*4+1] += e0.y * cur[i].x + e1.y * cur[i].y;
                macc[i*4+2] += e0.z * cur[i].x + e1.z * cur[i].y;
                macc[i*4+3] += e0.w * cur[i].x + e1.w * cur[i].y;
            }
        }
        // next iteration's kpart writes are ordered after barrier2 for all
        // waves, and es isn't rewritten until after the NEXT barrier1 -> safe.
    };

    for (int it = 0; it < NIT; it += 2) {
        body(xA, xB, it);
        body(xB, xA, it + 1);
    }

    // ---- macc: reduce over the 64 lanes (token dim) ----
    #pragma unroll
    for (int r = 0; r < 32; ++r) {
        float v = macc[r];
        v += __shfl_xor(v, 1);  v += __shfl_xor(v, 2);
        v += __shfl_xor(v, 4);  v += __shfl_xor(v, 8);
        v += __shfl_xor(v, 16); v += __shfl_xor(v, 32);
        macc[r] = v;
    }
    if (l == 0) {
        float* mb = ws + WS_M + (size_t)(b * 4) * NCH + c0;
        #pragma unroll
        for (int i = 0; i < 8; ++i) {
            #pragma unroll
            for (int h = 0; h < 4; ++h)
                __hip_atomic_fetch_add(mb + h * NCH + i, macc[i*4+h],
                                       __ATOMIC_RELAXED, __HIP_MEMORY_SCOPE_AGENT);
        }
    }

    // ---- S: per-head sums (h = l&3 invariant under xor 4/8/16/32) ----
    {
        float v = sacc;
        v += __shfl_xor(v, 4);  v += __shfl_xor(v, 8);
        v += __shfl_xor(v, 16); v += __shfl_xor(v, 32);
        if (l < 4) ssum[w][l] = v;
    }
    __syncthreads();
    if (tid < 4) {
        float s = 0.f;
        #pragma unroll
        for (int w2 = 0; w2 < 8; ++w2) s += ssum[w2][tid];
        __hip_atomic_fetch_add(ws + WS_S + b * 4 + tid, s,
                               __ATOMIC_RELAXED, __HIP_MEMORY_SCOPE_AGENT);
    }
}

// ---------- finalize: context = Wv*(m/S)+bv ; rc = Wr*context + br ----------
__global__ void ea3d_finalize(const float* __restrict__ Wv, const float* __restrict__ bv,
                              const float* __restrict__ Wr, const float* __restrict__ br,
                              float* __restrict__ ws)
{
    __shared__ float ctx[NB * 32];
    const int tid = threadIdx.x;
    if (tid < 128) {
        int b = tid >> 5, hv = tid & 31, h = hv >> 3;
        float inv = 1.0f / ws[WS_S + b * 4 + h];
        const float* m = ws + WS_M + (b * 4 + h) * NCH;
        const float* wvr = Wv + hv * NCH;
        float acc = 0.f;
        #pragma unroll
        for (int c = 0; c < NCH; ++c) acc += wvr[c] * m[c];
        ctx[b * 32 + hv] = acc * inv + bv[hv];
    }
    __syncthreads();
    int b = tid >> 6, c = tid & 63;
    const float* wrr = Wr + c * 32;
    const float* cb  = ctx + b * 32;
    float acc = br[c];
    #pragma unroll
    for (int hv = 0; hv < 32; ++hv) acc += wrr[hv] * cb[hv];
    ws[WS_RC + b * NCH + c] = acc;
}

// ---------- out = x + rc[b][c]  (nontemporal stores: don't evict x) ----------
__global__ __launch_bounds__(256)
void ea3d_add(const float* __restrict__ x, const float* __restrict__ ws,
              float* __restrict__ out)
{
    const int row = blockIdx.y;                 // b*64 + c
    const float rc = ws[WS_RC + row];
    const size_t base = (size_t)row * NTOK;
    const float4*  xp = (const float4*)(x + base);
    floatx4*       op = (floatx4*)(out + base);
    const int nvec = NTOK / 4;
    for (int i = blockIdx.x * blockDim.x + threadIdx.x; i < nvec;
         i += gridDim.x * blockDim.x) {
        float4 v = xp[i];
        floatx4 nv = { v.x + rc, v.y + rc, v.z + rc, v.w + rc };
        __builtin_nontemporal_store(nv, op + i);
    }
}

extern "C" void kernel_launch(void* const* d_in, const int* in_sizes, int n_in,
                              void* d_out, int out_size, void* d_ws, size_t ws_size,
                              hipStream_t stream)
{
    const float* x  = (const float*)d_in[0];
    const float* Wk = (const float*)d_in[1];
    // d_in[2]=bk (cancels in token-softmax); d_in[3]=Wq, d_in[4]=bq (softmax over
    // size-1 head-channel axis -> identically 1.0, so Wq/bq are dead)
    const float* Wv = (const float*)d_in[5];
    const float* bv = (const float*)d_in[6];
    const float* Wr = (const float*)d_in[7];
    const float* br = (const float*)d_in[8];
    float* out = (float*)d_out;
    float* ws  = (float*)d_ws;

    (void)hipMemsetAsync(ws, 0, WS_RC * sizeof(float), stream);  // zero S + m accumulators
    ea3d_reduce<<<dim3(GRIDX, NB), TPB, 0, stream>>>(x, Wk, ws);
    ea3d_finalize<<<1, 256, 0, stream>>>(Wv, bv, Wr, br, ws);
    ea3d_add<<<dim3(32, NB * NCH), 256, 0, stream>>>(x, ws, out);
}

// Round 11
// 190.726 us; speedup vs baseline: 4.8145x; 1.0967x over previous
//
#include <hip/hip_runtime.h>

#define NTOK 262144   // 64*64*64 tokens per batch
#define NCH  64
#define NB   4

#define TPB   512     // 8 waves
#define TILE  256     // tokens per tile (64 lanes x 4 tokens)
#define GRIDX 128     // blocks per batch -> 512 total = 2/CU
#define NIT   (NTOK / (GRIDX * TILE))   // 8 consecutive tiles per block

// ws layout (floats): S[4][4] @0, m[4][4][64] @16, rc[4][64] @1040
#define WS_S  0
#define WS_M  16
#define WS_RC 1040

// kpart slot stride in float4s (64 lanes + 2 pad)
#define KPS 66

typedef float floatx4 __attribute__((ext_vector_type(4)));   // native vec for nontemporal

// Single-x-read fused reduce, 1KB-extent loads.
// Wave w owns channels [8w, 8w+8); lane l owns tokens 4l..4l+3 (float4) of the
// 256-token tile; every load instruction covers 1KB contiguous.
// Keys: per-wave partial kk -> kpart LDS -> exp phase (waves 0-3) -> es LDS ->
// phase B accumulates m in registers (macc[32], static indexing only).
// Peak live VGPR ~105 (xr32 + kk16 + macc32 + sacc4 + addr) — fits the 128 cap
// (16 waves/CU) without spill (r5/r8/r9 lesson: stay under the cap by design).
__global__ __launch_bounds__(TPB)
void ea3d_reduce(const float* __restrict__ x, const float* __restrict__ Wk,
                 float* __restrict__ ws)
{
    __shared__ __align__(16) float wk4[NCH * 4];          // wk4[c][h]
    __shared__ __align__(16) float kpart[32 * KPS * 4];   // [w][j] slots of KPS float4
    __shared__ __align__(16) float es[4 * 64 * 4];        // [j][lane][h]
    __shared__ float ssum[4][4];

    const int tid = threadIdx.x;
    const int w   = tid >> 6;
    const int l   = tid & 63;
    const int b   = blockIdx.y;

    if (tid < 256) { int c = tid >> 2, h = tid & 3; wk4[(c << 2) + h] = Wk[h * NCH + c]; }
    __syncthreads();

    const int c0 = w << 3;                        // this wave's 8 channels
    const float* xb = x + ((size_t)b * NCH + c0) * NTOK;
    const size_t tokbase = (size_t)blockIdx.x * (TILE * NIT) + (l << 2);

    float macc[32];                               // macc[i*4+h], channel c0+i
    #pragma unroll
    for (int r = 0; r < 32; ++r) macc[r] = 0.f;
    float4 sacc4 = make_float4(0.f, 0.f, 0.f, 0.f);

    float4* kp = (float4*)kpart;

    for (int it = 0; it < NIT; ++it) {
        // ---- phase A: 8 x 1KB loads (this wave's channels, lane's 4 tokens) ----
        const float* xp = xb + tokbase + (size_t)it * TILE;
        float4 xr[8];
        #pragma unroll
        for (int i = 0; i < 8; ++i)
            xr[i] = *(const float4*)(xp + (size_t)i * NTOK);

        float kk[16];                             // kk[j*4+h], token j, head h
        #pragma unroll
        for (int r = 0; r < 16; ++r) kk[r] = 0.f;
        #pragma unroll
        for (int i = 0; i < 8; ++i) {
            float4 wv = *((const float4*)wk4 + (c0 + i));
            kk[0]  += wv.x * xr[i].x; kk[1]  += wv.y * xr[i].x;
            kk[2]  += wv.z * xr[i].x; kk[3]  += wv.w * xr[i].x;
            kk[4]  += wv.x * xr[i].y; kk[5]  += wv.y * xr[i].y;
            kk[6]  += wv.z * xr[i].y; kk[7]  += wv.w * xr[i].y;
            kk[8]  += wv.x * xr[i].z; kk[9]  += wv.y * xr[i].z;
            kk[10] += wv.z * xr[i].z; kk[11] += wv.w * xr[i].z;
            kk[12] += wv.x * xr[i].w; kk[13] += wv.y * xr[i].w;
            kk[14] += wv.z * xr[i].w; kk[15] += wv.w * xr[i].w;
        }
        #pragma unroll
        for (int j = 0; j < 4; ++j)               // contiguous lane-stride writes
            kp[((w << 2) + j) * KPS + l] =
                make_float4(kk[j*4+0], kk[j*4+1], kk[j*4+2], kk[j*4+3]);

        asm volatile("s_waitcnt lgkmcnt(0)" ::: "memory");
        __builtin_amdgcn_s_barrier();             // kpart ready (vmcnt NOT drained)
        asm volatile("" ::: "memory");

        // ---- exp phase: waves 0-3, thread -> token t = tid, all 4 heads ----
        if (tid < 256) {
            const int jj = tid & 3, lw = tid >> 2;
            float4 p = make_float4(0.f, 0.f, 0.f, 0.f);
            #pragma unroll
            for (int w2 = 0; w2 < 8; ++w2) {
                float4 qv = kp[((w2 << 2) + jj) * KPS + lw];
                p.x += qv.x; p.y += qv.y; p.z += qv.z; p.w += qv.w;
            }
            float4 e4 = make_float4(__expf(p.x), __expf(p.y), __expf(p.z), __expf(p.w));
            *(float4*)(es + ((jj << 6) + lw) * 4) = e4;
            sacc4.x += e4.x; sacc4.y += e4.y; sacc4.z += e4.z; sacc4.w += e4.w;
        }

        asm volatile("s_waitcnt lgkmcnt(0)" ::: "memory");
        __builtin_amdgcn_s_barrier();             // es ready
        asm volatile("" ::: "memory");

        // ---- phase B: m accumulation (registers, static) ----
        {
            float4 e0 = *(const float4*)(es + ((0 << 6) + l) * 4);
            float4 e1 = *(const float4*)(es + ((1 << 6) + l) * 4);
            float4 e2 = *(const float4*)(es + ((2 << 6) + l) * 4);
            float4 e3 = *(const float4*)(es + ((3 << 6) + l) * 4);
            #pragma unroll
            for (int i = 0; i < 8; ++i) {
                macc[i*4+0] += e0.x*xr[i].x + e1.x*xr[i].y + e2.x*xr[i].z + e3.x*xr[i].w;
                macc[i*4+1] += e0.y*xr[i].x + e1.y*xr[i].y + e2.y*xr[i].z + e3.y*xr[i].w;
                macc[i*4+2] += e0.z*xr[i].x + e1.z*xr[i].y + e2.z*xr[i].z + e3.z*xr[i].w;
                macc[i*4+3] += e0.w*xr[i].x + e1.w*xr[i].y + e2.w*xr[i].z + e3.w*xr[i].w;
            }
        }
        // next tile's kpart writes are ordered after barrier2 for all waves;
        // es is rewritten only after the NEXT barrier1 -> safe.
    }

    // ---- macc: reduce over this wave's 64 lanes (token dim), atomics per wave ----
    #pragma unroll
    for (int r = 0; r < 32; ++r) {
        float v = macc[r];
        v += __shfl_xor(v, 1);  v += __shfl_xor(v, 2);
        v += __shfl_xor(v, 4);  v += __shfl_xor(v, 8);
        v += __shfl_xor(v, 16); v += __shfl_xor(v, 32);
        macc[r] = v;
    }
    if (l == 0) {
        float* mb = ws + WS_M + (size_t)(b * 4) * NCH + c0;
        #pragma unroll
        for (int i = 0; i < 8; ++i) {
            #pragma unroll
            for (int h = 0; h < 4; ++h)
                __hip_atomic_fetch_add(mb + h * NCH + i, macc[i*4+h],
                                       __ATOMIC_RELAXED, __HIP_MEMORY_SCOPE_AGENT);
        }
    }

    // ---- S: waves 0-3 hold per-token e-sums (float4 over heads) ----
    if (w < 4) {
        float4 v = sacc4;
        #pragma unroll
        for (int off = 32; off; off >>= 1) {
            v.x += __shfl_xor(v.x, off); v.y += __shfl_xor(v.y, off);
            v.z += __shfl_xor(v.z, off); v.w += __shfl_xor(v.w, off);
        }
        if (l == 0) { ssum[w][0] = v.x; ssum[w][1] = v.y; ssum[w][2] = v.z; ssum[w][3] = v.w; }
    }
    __syncthreads();
    if (tid < 4) {
        float s = (ssum[0][tid] + ssum[1][tid]) + (ssum[2][tid] + ssum[3][tid]);
        __hip_atomic_fetch_add(ws + WS_S + b * 4 + tid, s,
                               __ATOMIC_RELAXED, __HIP_MEMORY_SCOPE_AGENT);
    }
}

// ---------- finalize: context = Wv*(m/S)+bv ; rc = Wr*context + br ----------
__global__ void ea3d_finalize(const float* __restrict__ Wv, const float* __restrict__ bv,
                              const float* __restrict__ Wr, const float* __restrict__ br,
                              float* __restrict__ ws)
{
    __shared__ float ctx[NB * 32];
    const int tid = threadIdx.x;
    if (tid < 128) {
        int b = tid >> 5, hv = tid & 31, h = hv >> 3;
        float inv = 1.0f / ws[WS_S + b * 4 + h];
        const float* m = ws + WS_M + (b * 4 + h) * NCH;
        const float* wvr = Wv + hv * NCH;
        float acc = 0.f;
        #pragma unroll
        for (int c = 0; c < NCH; ++c) acc += wvr[c] * m[c];
        ctx[b * 32 + hv] = acc * inv + bv[hv];
    }
    __syncthreads();
    int b = tid >> 6, c = tid & 63;
    const float* wrr = Wr + c * 32;
    const float* cb  = ctx + b * 32;
    float acc = br[c];
    #pragma unroll
    for (int hv = 0; hv < 32; ++hv) acc += wrr[hv] * cb[hv];
    ws[WS_RC + b * NCH + c] = acc;
}

// ---------- out = x + rc[b][c]  (nontemporal stores: don't evict x) ----------
__global__ __launch_bounds__(256)
void ea3d_add(const float* __restrict__ x, const float* __restrict__ ws,
              float* __restrict__ out)
{
    const int row = blockIdx.y;                 // b*64 + c
    const float rc = ws[WS_RC + row];
    const size_t base = (size_t)row * NTOK;
    const float4*  xp = (const float4*)(x + base);
    floatx4*       op = (floatx4*)(out + base);
    const int nvec = NTOK / 4;
    for (int i = blockIdx.x * blockDim.x + threadIdx.x; i < nvec;
         i += gridDim.x * blockDim.x) {
        float4 v = xp[i];
        floatx4 nv = { v.x + rc, v.y + rc, v.z + rc, v.w + rc };
        __builtin_nontemporal_store(nv, op + i);
    }
}

extern "C" void kernel_launch(void* const* d_in, const int* in_sizes, int n_in,
                              void* d_out, int out_size, void* d_ws, size_t ws_size,
                              hipStream_t stream)
{
    const float* x  = (const float*)d_in[0];
    const float* Wk = (const float*)d_in[1];
    // d_in[2]=bk (cancels in token-softmax); d_in[3]=Wq, d_in[4]=bq (softmax over
    // size-1 head-channel axis -> identically 1.0, so Wq/bq are dead)
    const float* Wv = (const float*)d_in[5];
    const float* bv = (const float*)d_in[6];
    const float* Wr = (const float*)d_in[7];
    const float* br = (const float*)d_in[8];
    float* out = (float*)d_out;
    float* ws  = (float*)d_ws;

    (void)hipMemsetAsync(ws, 0, WS_RC * sizeof(float), stream);  // zero S + m accumulators
    ea3d_reduce<<<dim3(GRIDX, NB), TPB, 0, stream>>>(x, Wk, ws);
    ea3d_finalize<<<1, 256, 0, stream>>>(Wv, bv, Wr, br, ws);
    ea3d_add<<<dim3(32, NB * NCH), 256, 0, stream>>>(x, ws, out);
}